// Round 12
// baseline (253.632 us; speedup 1.0000x reference)
//
#include <hip/hip_runtime.h>
#include <math.h>

#define BB    4
#define CIN   3
#define NN    8192
#define NTOT  32768
#define WD    128
#define MODES 32
#define DEG   16
#define NEDGE 17
#define TWOPI 6.28318530717958647692f

typedef _Float16 f16;
typedef _Float16 f16x8 __attribute__((ext_vector_type(8)));
typedef _Float16 f16x4 __attribute__((ext_vector_type(4)));
typedef _Float16 f16x2 __attribute__((ext_vector_type(2)));
typedef float    f32x4 __attribute__((ext_vector_type(4)));

__device__ __forceinline__ float gelu_f(float v) {
    return 0.5f * v * (1.0f + erff(v * 0.7071067811865476f));
}

// XCD-affinity swizzle, 1024-block kernels, graph = ebid>>8.
__device__ __forceinline__ int swz1024(int bid) {
    int xcd = bid & 7;
    int g = xcd >> 1;
    int local = ((bid >> 3) << 1) | (xcd & 1);
    return (g << 8) | local;
}

// ---------------- one-time setup (tables + casts + twr fused) ----------------

__global__ __launch_bounds__(256) void k_setup(const float* __restrict__ f2w,
        const float* __restrict__ ww, const float* __restrict__ dec1w,
        const float* __restrict__ ecw, const float* __restrict__ wr,
        const float* __restrict__ wi, f16* __restrict__ nkbf,
        f16* __restrict__ tknh, f16* __restrict__ wcat, f16* __restrict__ w1h,
        f16* __restrict__ ecwh, f16* __restrict__ wrT, f16* __restrict__ wiT) {
    int bid = blockIdx.x;
    if (bid < 1024) {
        // trig tables
        int idx = bid * 256 + threadIdx.x;         // NN*MODES
        int n = idx >> 5;
        int k = idx & 31;
        int m = (n * k) & (NN - 1);
        float ang = (float)m * (TWOPI / (float)NN);
        float s, c;
        sincosf(ang, &s, &c);
        if (k >= 1) {
            nkbf[n * 64 + 2 * k - 2] = (f16)c;
            nkbf[n * 64 + 2 * k - 1] = (f16)s;
            tknh[(2 * k) * NN + n]     = (f16)c;
            tknh[(2 * k + 1) * NN + n] = (f16)s;
        } else {
            nkbf[n * 64 + 62] = (f16)0.f;
            nkbf[n * 64 + 63] = (f16)0.f;
            tknh[n]      = (f16)1.f;
            tknh[NN + n] = (f16)0.f;
        }
    } else if (bid < 1728) {
        // weight casts
        int idx = (bid - 1024) * 256 + threadIdx.x;  // 180224 total
        if (idx < 131072) {
            int lay = idx >> 15, rem = idx & 32767;
            int o = rem >> 8, k = rem & 255;
            float v = (k < 128) ? f2w[(lay * WD + o) * WD + k]
                                : ww[(lay * WD + o) * WD + (k - 128)];
            wcat[idx] = (f16)v;
        } else if (idx < 163840) {
            int i2 = idx - 131072;
            w1h[i2] = (f16)dec1w[i2];
        } else if (idx < 180224) {
            int i3 = idx - 163840;
            ecwh[i3] = (f16)ecw[i3];
        }
    } else {
        // wr/wi [lay][i][o][k] -> [lay][k][i][o] (f16)
        int twb = bid - 1728;                      // 0..1023
        const float* src = (twb >> 9) ? wi : wr;
        f16*         dst = (twb >> 9) ? wiT : wrT;
        int xx = twb & 511;
        int ib = xx >> 7, i = xx & 127;
        __shared__ float tile[128][33];
        const float* s = src + ((size_t)(ib * WD + i) * WD) * MODES;
        for (int e = threadIdx.x; e < WD * MODES; e += 256) {
            int o = e >> 5, k = e & 31;
            tile[o][k] = s[e];
        }
        __syncthreads();
        f16* d = dst + (size_t)ib * (MODES * WD * WD) + i * WD;
        for (int e = threadIdx.x; e < WD * MODES; e += 256) {
            int k = e >> 7, o = e & 127;
            d[(size_t)k * WD * WD + o] = (f16)tile[o][k];
        }
    }
}

// ---------------- encoder ----------------

__global__ __launch_bounds__(256) void k_enc_fused(const float* __restrict__ x,
        const int* __restrict__ src, const float* __restrict__ ew,
        const float* __restrict__ eb, f16* __restrict__ h1) {
    int tid = threadIdx.x;
    int t0 = blockIdx.x * 64;
    int b = t0 >> 13;
    const float* xg0 = x + (size_t)(b * 3 + 0) * NN;
    const float* xg1 = x + (size_t)(b * 3 + 1) * NN;
    const float* xg2 = x + (size_t)(b * 3 + 2) * NN;
    __shared__ float agg[64][8];
    {
        int nl = tid >> 2;
        int sub = tid & 3;
        int t = t0 + nl;
        int4 sl = *(const int4*)&src[t * DEG + sub * 4];
        int i0 = sl.x & (NN - 1), i1 = sl.y & (NN - 1);
        int i2 = sl.z & (NN - 1), i3 = sl.w & (NN - 1);
        float a0 = xg0[i0] + xg0[i1] + xg0[i2] + xg0[i3];
        float a1 = xg1[i0] + xg1[i1] + xg1[i2] + xg1[i3];
        float a2 = xg2[i0] + xg2[i1] + xg2[i2] + xg2[i3];
        a0 += __shfl_xor(a0, 1); a0 += __shfl_xor(a0, 2);
        a1 += __shfl_xor(a1, 1); a1 += __shfl_xor(a1, 2);
        a2 += __shfl_xor(a2, 1); a2 += __shfl_xor(a2, 2);
        if (sub == 0) {
            int n_ = t & (NN - 1);
            float xi0 = xg0[n_], xi1 = xg1[n_], xi2 = xg2[n_];
            agg[nl][0] = xi0; agg[nl][1] = xi1; agg[nl][2] = xi2;
            agg[nl][3] = (a0 + xi0) * (1.f / NEDGE) - xi0;
            agg[nl][4] = (a1 + xi1) * (1.f / NEDGE) - xi1;
            agg[nl][5] = (a2 + xi2) * (1.f / NEDGE) - xi2;
        }
    }
    __syncthreads();
    int o = tid & 127, half = tid >> 7;
    const float* w = ew + o * 6;
    float w0 = w[0], w1 = w[1], w2 = w[2], w3 = w[3], w4 = w[4], w5 = w[5];
    float bb = eb[o];
    #pragma unroll 4
    for (int g = 0; g < 32; ++g) {
        int n2 = half * 32 + g;
        float acc = bb + w0 * agg[n2][0] + w1 * agg[n2][1] + w2 * agg[n2][2]
                       + w3 * agg[n2][3] + w4 * agg[n2][4] + w5 * agg[n2][5];
        h1[(size_t)(t0 + n2) * WD + o] = (f16)gelu_f(acc);
    }
}

// gather: 4 nodes per wave-instruction, 32 nodes/block. At[node][c] stride 136.
__device__ __forceinline__ void gather4_to_lds(const f16* __restrict__ hin,
        const int* __restrict__ src, int t0, int tid, f16* At) {
    int wv = tid >> 6;
    int lane = tid & 63;
    int nd = lane >> 4;
    int cl = lane & 15;
    #pragma unroll
    for (int it = 0; it < 2; ++it) {
        int nl = wv * 8 + it * 4 + nd;
        int t = t0 + nl;
        f16x8 v = *(const f16x8*)&hin[(size_t)t * WD + cl * 8];
        float a0 = (float)v[0], a1 = (float)v[1], a2 = (float)v[2], a3 = (float)v[3];
        float a4 = (float)v[4], a5 = (float)v[5], a6 = (float)v[6], a7 = (float)v[7];
        const int* sl = src + t * DEG;
        #pragma unroll
        for (int d = 0; d < DEG; ++d) {
            int nb = sl[d];
            f16x8 u = *(const f16x8*)&hin[(size_t)nb * WD + cl * 8];
            a0 += (float)u[0]; a1 += (float)u[1]; a2 += (float)u[2]; a3 += (float)u[3];
            a4 += (float)u[4]; a5 += (float)u[5]; a6 += (float)u[6]; a7 += (float)u[7];
        }
        const float sc = 1.f / NEDGE;
        f16x8 r;
        r[0] = (f16)(a0 * sc); r[1] = (f16)(a1 * sc); r[2] = (f16)(a2 * sc); r[3] = (f16)(a3 * sc);
        r[4] = (f16)(a4 * sc); r[5] = (f16)(a5 * sc); r[6] = (f16)(a6 * sc); r[7] = (f16)(a7 * sc);
        *(f16x8*)&At[nl * 136 + cl * 8] = r;
    }
}

// gather 32-node mean -> MFMA (A=ecwh) -> h f16 [b][c][n]
__global__ __launch_bounds__(256, 4) void k_gather_lin_mfma(
        const f16* __restrict__ hin, const int* __restrict__ src,
        const f16* __restrict__ ecwh, const float* __restrict__ bias,
        f16* __restrict__ outp) {
    int tid = threadIdx.x;
    int ebid = swz1024(blockIdx.x);
    int t0 = ebid * 32;
    int b = ebid >> 8;
    int n0 = (ebid & 255) * 32;
    __shared__ f16 At[32 * 136];
    gather4_to_lds(hin, src, t0, tid, At);
    __syncthreads();
    int w = tid >> 6, l = tid & 63, lg = l >> 4, ln = l & 15;
    f32x4 acc[2][2] = {};
    #pragma unroll
    for (int kc = 0; kc < 4; ++kc) {
        f16x8 wa[2], ab[2];
        #pragma unroll
        for (int i = 0; i < 2; ++i)
            wa[i] = *(const f16x8*)&ecwh[((2 * w + i) * 16 + ln) * WD + kc * 32 + lg * 8];
        #pragma unroll
        for (int j = 0; j < 2; ++j)
            ab[j] = *(const f16x8*)&At[(j * 16 + ln) * 136 + kc * 32 + lg * 8];
        #pragma unroll
        for (int i = 0; i < 2; ++i)
            #pragma unroll
            for (int j = 0; j < 2; ++j)
                acc[i][j] = __builtin_amdgcn_mfma_f32_16x16x32_f16(wa[i], ab[j], acc[i][j], 0, 0, 0);
    }
    #pragma unroll
    for (int i = 0; i < 2; ++i) {
        int cb = (2 * w + i) * 16 + lg * 4;
        float b0 = bias[cb], b1 = bias[cb + 1], b2 = bias[cb + 2], b3 = bias[cb + 3];
        #pragma unroll
        for (int j = 0; j < 2; ++j) {
            int n_ = n0 + j * 16 + ln;
            outp[(size_t)(b * WD + cb + 0) * NN + n_] = (f16)(acc[i][j][0] + b0);
            outp[(size_t)(b * WD + cb + 1) * NN + n_] = (f16)(acc[i][j][1] + b1);
            outp[(size_t)(b * WD + cb + 2) * NN + n_] = (f16)(acc[i][j][2] + b2);
            outp[(size_t)(b * WD + cb + 3) * NN + n_] = (f16)(acc[i][j][3] + b3);
        }
    }
}

// ---------------- FNO block pieces ----------------

// DFT via MFMA + fused sum-of-squares: part[sp][512r][64kc], sqp[sp][512r]
__global__ __launch_bounds__(256, 2) void k_dft_mfma(const f16* __restrict__ h,
        const f16* __restrict__ tknh, float* __restrict__ part,
        float* __restrict__ sqp) {
    int bid = blockIdx.x;
    int sp = bid >> 3;                   // 0..31
    int r0 = (bid & 7) * 64;
    int wv = threadIdx.x >> 6, l = threadIdx.x & 63, lg = l >> 4, ln = l & 15;
    int row = r0 + wv * 16;
    f32x4 acc[4] = {};
    const f16* ha = h + (size_t)(row + ln) * NN + sp * 256 + lg * 8;
    const f16* tb = tknh + (size_t)ln * NN + sp * 256 + lg * 8;
    float sq = 0.f;
    #pragma unroll
    for (int st = 0; st < 8; ++st) {
        f16x8 a = *(const f16x8*)&ha[st * 32];
        #pragma unroll
        for (int j = 0; j < 8; ++j) { float f = (float)a[j]; sq += f * f; }
        #pragma unroll
        for (int tj = 0; tj < 4; ++tj) {
            f16x8 b = *(const f16x8*)&tb[(size_t)(tj * 16) * NN + st * 32];
            acc[tj] = __builtin_amdgcn_mfma_f32_16x16x32_f16(a, b, acc[tj], 0, 0, 0);
        }
    }
    float* pr = part + ((size_t)sp * 512 + row) * 64;
    #pragma unroll
    for (int tj = 0; tj < 4; ++tj)
        #pragma unroll
        for (int q = 0; q < 4; ++q)
            pr[(lg * 4 + q) * 64 + tj * 16 + ln] = acc[tj][q];
    sq += __shfl_xor(sq, 16);
    sq += __shfl_xor(sq, 32);
    if (lg == 0) sqp[sp * 512 + row + ln] = sq;
}

// stats from part[kc=0] + sqp; combine partials; write vf. No h re-read.
__global__ __launch_bounds__(256) void k_dft_fin3(const float* __restrict__ part,
        const float* __restrict__ sqp, float* __restrict__ vf) {
    int row = blockIdx.x * 4 + (threadIdx.x >> 6);
    int lane = threadIdx.x & 63;
    float D = 0.f;
    #pragma unroll
    for (int p = 0; p < 32; ++p)
        D += part[(size_t)(p * 512 + row) * 64 + lane];
    float sq = (lane < 32) ? sqp[lane * 512 + row] : 0.f;
    sq += __shfl_xor(sq, 1);
    sq += __shfl_xor(sq, 2);
    sq += __shfl_xor(sq, 4);
    sq += __shfl_xor(sq, 8);
    sq += __shfl_xor(sq, 16);
    sq += __shfl_xor(sq, 32);
    float D0 = __shfl(D, 0);
    float mu  = D0 * (1.f / NN);
    float var = sq * (1.f / NN) - mu * mu;
    float s1  = 1.f / sqrtf(fmaxf(var, 0.f) + 1e-5f);
    float v;
    if (lane < 2) v = 0.f;
    else          v = (lane & 1) ? -D * s1 : D * s1;
    vf[row * 64 + lane] = v;
}

__global__ __launch_bounds__(128) void k_spec(const float* __restrict__ vf,
        const f16* __restrict__ wrT, const f16* __restrict__ wiT,
        float* __restrict__ of, int lay) {
    int b = blockIdx.x / 31;
    int k = blockIdx.x - b * 31 + 1;
    int o = threadIdx.x;
    __shared__ float vr[WD], vi[WD];
    vr[o] = vf[(b * WD + o) * 64 + 2 * k];
    vi[o] = vf[(b * WD + o) * 64 + 2 * k + 1];
    __syncthreads();
    const f16* wrk = wrT + ((size_t)(lay * MODES + k) * WD) * WD + o;
    const f16* wik = wiT + ((size_t)(lay * MODES + k) * WD) * WD + o;
    float ore = 0.f, oim = 0.f;
    for (int i = 0; i < WD; ++i) {
        float a = vr[i], bq = vi[i];
        float w0 = (float)wrk[i * WD], w1 = (float)wik[i * WD];
        ore += a * w0 - bq * w1;
        oim += a * w1 + bq * w0;
    }
    of[(b * WD + o) * 64 + 2 * k]     = ore;
    of[(b * WD + o) * 64 + 2 * k + 1] = oim;
}

// sigma2 + fold f1_w -> GB f16 [b][c][64] (slots 0..61 = kc 2..63; 62,63 = 0)
__global__ __launch_bounds__(256) void k_coef(const float* __restrict__ of,
        const float* __restrict__ f1w, f16* __restrict__ GB) {
    int b = blockIdx.x >> 3;
    int c0 = (blockIdx.x & 7) * 16;
    __shared__ float ofl[WD][66];
    __shared__ float fw[16][WD];
    __shared__ float scl[WD];
    for (int e = threadIdx.x; e < WD * 64; e += 256) {
        int o = e >> 6, kc = e & 63;
        ofl[o][kc] = of[(b * WD + o) * 64 + kc];
    }
    for (int e = threadIdx.x; e < 16 * WD; e += 256) {
        int cl = e >> 7, i = e & 127;
        fw[cl][i] = f1w[(c0 + cl) * WD + i];
    }
    __syncthreads();
    if (threadIdx.x < WD) {
        int o = threadIdx.x;
        float s = 0.f;
        for (int kc = 2; kc < 64; ++kc) { float v = ofl[o][kc]; s += v * v; }
        float var = s * (2.f / ((float)NN * (float)NN));
        scl[o] = (2.f / (float)NN) / sqrtf(var + 1e-5f);
    }
    __syncthreads();
    for (int e = threadIdx.x; e < 16 * 62; e += 256) {
        int cl = e / 62, kc = e - cl * 62 + 2;
        float a = 0.f;
        for (int o = 0; o < WD; ++o)
            a += fw[cl][o] * (ofl[o][kc] * scl[o]);
        if (kc & 1) a = -a;
        GB[(b * WD + c0 + cl) * 64 + (kc - 2)] = (f16)a;
    }
    if (threadIdx.x < 32) {
        int cl = threadIdx.x >> 1;
        GB[(b * WD + c0 + cl) * 64 + 62 + (threadIdx.x & 1)] = (f16)0.f;
    }
}

// fused FNO tail (f16 h in/out): t = gelu(G@tbl + f1b); hnew = gelu(f2@t + w@h + b)
// hn may be null (last layer: only node-major hfo consumed downstream).
__global__ __launch_bounds__(256, 2) void k_fno(const f16* __restrict__ hc,
        const f16* __restrict__ GB, const f16* __restrict__ nkbf,
        const f16* __restrict__ wcat, const float* __restrict__ f1b,
        const float* __restrict__ f2b, const float* __restrict__ wb,
        f16* __restrict__ hn, f16* __restrict__ hfo) {
    int tid = threadIdx.x;
    int b = blockIdx.x >> 7;
    int n0 = (blockIdx.x & 127) * 64;
    int w = tid >> 6, l = tid & 63, lg = l >> 4, ln = l & 15;
    __shared__ f16 tS[64 * 136];   // [n][c]
    __shared__ f16 hS[64 * 136];
    f16x8 hreg[4];
    #pragma unroll
    for (int p = 0; p < 4; ++p) {
        int idx = p * 256 + tid;
        int c = idx >> 3, n8 = idx & 7;
        hreg[p] = *(const f16x8*)&hc[(size_t)(b * WD + c) * NN + n0 + n8 * 8];
    }
    // stage 1: t = G @ tbl  (K=64)
    f32x4 acc1[2][4] = {};
    #pragma unroll
    for (int kc = 0; kc < 2; ++kc) {
        f16x8 ga[2], tb[4];
        #pragma unroll
        for (int i = 0; i < 2; ++i)
            ga[i] = *(const f16x8*)&GB[(size_t)(b * WD + (2 * w + i) * 16 + ln) * 64 + kc * 32 + lg * 8];
        #pragma unroll
        for (int j = 0; j < 4; ++j)
            tb[j] = *(const f16x8*)&nkbf[(size_t)(n0 + j * 16 + ln) * 64 + kc * 32 + lg * 8];
        #pragma unroll
        for (int i = 0; i < 2; ++i)
            #pragma unroll
            for (int j = 0; j < 4; ++j)
                acc1[i][j] = __builtin_amdgcn_mfma_f32_16x16x32_f16(ga[i], tb[j], acc1[i][j], 0, 0, 0);
    }
    #pragma unroll
    for (int i = 0; i < 2; ++i) {
        int cb = (2 * w + i) * 16 + lg * 4;
        float b0 = f1b[cb], b1 = f1b[cb + 1], b2 = f1b[cb + 2], b3 = f1b[cb + 3];
        #pragma unroll
        for (int j = 0; j < 4; ++j) {
            int n_ = j * 16 + ln;
            f16x4 o4;
            o4[0] = (f16)gelu_f(acc1[i][j][0] + b0);
            o4[1] = (f16)gelu_f(acc1[i][j][1] + b1);
            o4[2] = (f16)gelu_f(acc1[i][j][2] + b2);
            o4[3] = (f16)gelu_f(acc1[i][j][3] + b3);
            *(f16x4*)&tS[n_ * 136 + cb] = o4;
        }
    }
    #pragma unroll
    for (int p = 0; p < 4; ++p) {
        int idx = p * 256 + tid;
        int c = idx >> 3, n8 = idx & 7;
        #pragma unroll
        for (int q = 0; q < 8; ++q)
            hS[(n8 * 8 + q) * 136 + c] = hreg[p][q];
    }
    __syncthreads();
    // stage 2: D = Wcat @ [t ; h]  (K=256)
    f32x4 acc2[2][4] = {};
    #pragma unroll
    for (int kc = 0; kc < 8; ++kc) {
        const f16* Xs = (kc < 4) ? (tS + kc * 32) : (hS + (kc - 4) * 32);
        f16x8 wa[2], xb[4];
        #pragma unroll
        for (int i = 0; i < 2; ++i)
            wa[i] = *(const f16x8*)&wcat[(size_t)((2 * w + i) * 16 + ln) * 256 + kc * 32 + lg * 8];
        #pragma unroll
        for (int j = 0; j < 4; ++j)
            xb[j] = *(const f16x8*)&Xs[(j * 16 + ln) * 136 + lg * 8];
        #pragma unroll
        for (int i = 0; i < 2; ++i)
            #pragma unroll
            for (int j = 0; j < 4; ++j)
                acc2[i][j] = __builtin_amdgcn_mfma_f32_16x16x32_f16(wa[i], xb[j], acc2[i][j], 0, 0, 0);
    }
    #pragma unroll
    for (int i = 0; i < 2; ++i) {
        int ob = (2 * w + i) * 16 + lg * 4;
        float b0 = f2b[ob] + wb[ob];
        float b1 = f2b[ob + 1] + wb[ob + 1];
        float b2 = f2b[ob + 2] + wb[ob + 2];
        float b3 = f2b[ob + 3] + wb[ob + 3];
        #pragma unroll
        for (int j = 0; j < 4; ++j) {
            int n_ = n0 + j * 16 + ln;
            f16 v0 = (f16)gelu_f(acc2[i][j][0] + b0);
            f16 v1 = (f16)gelu_f(acc2[i][j][1] + b1);
            f16 v2 = (f16)gelu_f(acc2[i][j][2] + b2);
            f16 v3 = (f16)gelu_f(acc2[i][j][3] + b3);
            if (hn) {
                hn[(size_t)(b * WD + ob + 0) * NN + n_] = v0;
                hn[(size_t)(b * WD + ob + 1) * NN + n_] = v1;
                hn[(size_t)(b * WD + ob + 2) * NN + n_] = v2;
                hn[(size_t)(b * WD + ob + 3) * NN + n_] = v3;
            }
            if (hfo) {
                f16x4 o4; o4[0] = v0; o4[1] = v1; o4[2] = v2; o4[3] = v3;
                *(f16x4*)&hfo[(size_t)(b * NN + n_) * WD + ob] = o4;
            }
        }
    }
}

// ---------------- decoder ----------------

__global__ __launch_bounds__(256, 4) void k_dec_mfma(const f16* __restrict__ hf,
        const int* __restrict__ src, const f16* __restrict__ w1h,
        const float* __restrict__ b1, const float* __restrict__ w3,
        const float* __restrict__ b3, float* __restrict__ z) {
    int tid = threadIdx.x;
    int t0 = swz1024(blockIdx.x) * 32;
    __shared__ f16 At[32 * 136];
    __shared__ float zl[16 * 32];
    gather4_to_lds(hf, src, t0, tid, At);
    __syncthreads();
    int w = tid >> 6, l = tid & 63, lg = l >> 4, ln = l & 15;
    f32x4 acc[4][2] = {};
    #pragma unroll
    for (int kc = 0; kc < 4; ++kc) {
        f16x8 wa[4], ab[2];
        #pragma unroll
        for (int u = 0; u < 4; ++u)
            wa[u] = *(const f16x8*)&w1h[(size_t)((w * 4 + u) * 16 + ln) * WD + kc * 32 + lg * 8];
        #pragma unroll
        for (int j = 0; j < 2; ++j)
            ab[j] = *(const f16x8*)&At[(j * 16 + ln) * 136 + kc * 32 + lg * 8];
        #pragma unroll
        for (int u = 0; u < 4; ++u)
            #pragma unroll
            for (int j = 0; j < 2; ++j)
                acc[u][j] = __builtin_amdgcn_mfma_f32_16x16x32_f16(wa[u], ab[j], acc[u][j], 0, 0, 0);
    }
    float pz[2] = {0.f, 0.f};
    #pragma unroll
    for (int u = 0; u < 4; ++u) {
        int jb = (w * 4 + u) * 16 + lg * 4;
        float b1r0 = b1[jb], b1r1 = b1[jb + 1], b1r2 = b1[jb + 2], b1r3 = b1[jb + 3];
        float w3r0 = w3[jb], w3r1 = w3[jb + 1], w3r2 = w3[jb + 2], w3r3 = w3[jb + 3];
        #pragma unroll
        for (int j = 0; j < 2; ++j) {
            pz[j] += w3r0 * gelu_f(acc[u][j][0] + b1r0);
            pz[j] += w3r1 * gelu_f(acc[u][j][1] + b1r1);
            pz[j] += w3r2 * gelu_f(acc[u][j][2] + b1r2);
            pz[j] += w3r3 * gelu_f(acc[u][j][3] + b1r3);
        }
    }
    #pragma unroll
    for (int j = 0; j < 2; ++j)
        zl[(w * 4 + lg) * 32 + j * 16 + ln] = pz[j];
    __syncthreads();
    if (tid < 32) {
        float s = b3[0];
        #pragma unroll
        for (int g = 0; g < 16; ++g) s += zl[g * 32 + tid];
        z[t0 + tid] = s;
    }
}

__global__ __launch_bounds__(256) void k_out(const float* __restrict__ z,
        const int* __restrict__ src, float* __restrict__ outp) {
    int t = blockIdx.x * 256 + threadIdx.x;
    if (t >= NTOT) return;
    const int* sl = src + t * DEG;
    float acc = z[t];
    #pragma unroll
    for (int d = 0; d < DEG; ++d) acc += z[sl[d]];
    outp[t] = acc * (1.f / NEDGE);
}

// ---------------- host launcher ----------------

extern "C" void kernel_launch(void* const* d_in, const int* in_sizes, int n_in,
                              void* d_out, int out_size, void* d_ws, size_t ws_size,
                              hipStream_t stream) {
    const float* x       = (const float*)d_in[0];
    const int*   ei      = (const int*)  d_in[1];   // row0 = src
    const float* enc_e_w = (const float*)d_in[2];
    const float* enc_e_b = (const float*)d_in[3];
    const float* enc_c_w = (const float*)d_in[4];
    const float* enc_c_b = (const float*)d_in[5];
    const float* wr      = (const float*)d_in[6];
    const float* wi      = (const float*)d_in[7];
    const float* w_w     = (const float*)d_in[8];
    const float* w_b     = (const float*)d_in[9];
    const float* f1_w    = (const float*)d_in[10];
    const float* f1_b    = (const float*)d_in[11];
    const float* f2_w    = (const float*)d_in[12];
    const float* f2_b    = (const float*)d_in[13];
    const float* dec1_w  = (const float*)d_in[14];
    const float* dec1_b  = (const float*)d_in[15];
    const float* dec3_w  = (const float*)d_in[16];
    const float* dec3_b  = (const float*)d_in[17];
    float* outp = (float*)d_out;
    float* ws = (float*)d_ws;

    float* part  = ws;                         // 1,048,576 (32 splits)
    float* sqp   = part + 1048576;             // 16,384
    float* zb    = sqp + 16384;                // 32,768
    float* vf    = zb + 32768;                 // 32,768
    float* of    = vf + 32768;                 // 32,768
    f16* wrT  = (f16*)(of + 32768);            // 2,097,152 f16
    f16* wiT  = wrT + 2097152;                 // 2,097,152
    f16* h1h  = wiT + 2097152;                 // 4,194,304 (enc feat / dec hf)
    f16* H0   = h1h + 4194304;                 // 4,194,304
    f16* H1   = H0 + 4194304;                  // 4,194,304
    f16* nkbf = H1 + 4194304;                  // 524,288
    f16* tknh = nkbf + 524288;                 // 524,288
    f16* wcatB= tknh + 524288;                 // 131,072
    f16* w1h  = wcatB + 131072;                // 32,768
    f16* ecwh = w1h + 32768;                   // 16,384
    f16* GB   = ecwh + 16384;                  // 32,768
    f16* hfh  = h1h;

    k_setup<<<2752, 256, 0, stream>>>(f2_w, w_w, dec1_w, enc_c_w, wr, wi,
                                      nkbf, tknh, wcatB, w1h, ecwh, wrT, wiT);

    // encoder
    k_enc_fused<<<512, 256, 0, stream>>>(x, ei, enc_e_w, enc_e_b, h1h);
    k_gather_lin_mfma<<<1024, 256, 0, stream>>>(h1h, ei, ecwh, enc_c_b, H0);

    for (int lay = 0; lay < 4; ++lay) {
        f16* hc = (lay & 1) ? H1 : H0;
        f16* hn = (lay & 1) ? H0 : H1;
        k_dft_mfma<<<256, 256, 0, stream>>>(hc, tknh, part, sqp);
        k_dft_fin3<<<128, 256, 0, stream>>>(part, sqp, vf);
        k_spec<<<124, 128, 0, stream>>>(vf, wrT, wiT, of, lay);
        k_coef<<<32, 256, 0, stream>>>(of, f1_w + lay * WD * WD, GB);
        k_fno<<<512, 256, 0, stream>>>(hc, GB, nkbf, wcatB + lay * WD * 256,
                                       f1_b + lay * WD, f2_b + lay * WD,
                                       w_b + lay * WD,
                                       (lay == 3) ? (f16*)nullptr : hn,
                                       (lay == 3) ? hfh : (f16*)nullptr);
    }
    // node-major final h in hfh

    k_dec_mfma<<<1024, 256, 0, stream>>>(hfh, ei, w1h, dec1_b, dec3_w, dec3_b, zb);
    k_out<<<128, 256, 0, stream>>>(zb, ei, outp);
}

// Round 13
// 239.851 us; speedup vs baseline: 1.0575x; 1.0575x over previous
//
#include <hip/hip_runtime.h>
#include <math.h>

#define BB    4
#define CIN   3
#define NN    8192
#define NTOT  32768
#define WD    128
#define MODES 32
#define DEG   16
#define NEDGE 17
#define TWOPI 6.28318530717958647692f

typedef _Float16 f16;
typedef _Float16 f16x8 __attribute__((ext_vector_type(8)));
typedef _Float16 f16x4 __attribute__((ext_vector_type(4)));
typedef _Float16 f16x2 __attribute__((ext_vector_type(2)));
typedef float    f32x4 __attribute__((ext_vector_type(4)));

__device__ __forceinline__ float gelu_f(float v) {
    return 0.5f * v * (1.0f + erff(v * 0.7071067811865476f));
}

// XCD-affinity swizzle, 1024-block kernels, graph = ebid>>8.
__device__ __forceinline__ int swz1024(int bid) {
    int xcd = bid & 7;
    int g = xcd >> 1;
    int local = ((bid >> 3) << 1) | (xcd & 1);
    return (g << 8) | local;
}

// ---------------- one-time setup (tables + casts + twr fused) ----------------

__global__ __launch_bounds__(256) void k_setup(const float* __restrict__ f2w,
        const float* __restrict__ ww, const float* __restrict__ dec1w,
        const float* __restrict__ ecw, const float* __restrict__ wr,
        const float* __restrict__ wi, f16* __restrict__ nkbf,
        f16* __restrict__ tknh, f16* __restrict__ wcat, f16* __restrict__ w1h,
        f16* __restrict__ ecwh, float* __restrict__ wrT, float* __restrict__ wiT) {
    int bid = blockIdx.x;
    if (bid < 1024) {
        // trig tables
        int idx = bid * 256 + threadIdx.x;         // NN*MODES
        int n = idx >> 5;
        int k = idx & 31;
        int m = (n * k) & (NN - 1);
        float ang = (float)m * (TWOPI / (float)NN);
        float s, c;
        sincosf(ang, &s, &c);
        if (k >= 1) {
            nkbf[n * 64 + 2 * k - 2] = (f16)c;
            nkbf[n * 64 + 2 * k - 1] = (f16)s;
            tknh[(2 * k) * NN + n]     = (f16)c;
            tknh[(2 * k + 1) * NN + n] = (f16)s;
        } else {
            nkbf[n * 64 + 62] = (f16)0.f;
            nkbf[n * 64 + 63] = (f16)0.f;
            tknh[n]      = (f16)1.f;
            tknh[NN + n] = (f16)0.f;
        }
    } else if (bid < 1728) {
        // weight casts
        int idx = (bid - 1024) * 256 + threadIdx.x;  // 180224 total
        if (idx < 131072) {
            int lay = idx >> 15, rem = idx & 32767;
            int o = rem >> 8, k = rem & 255;
            float v = (k < 128) ? f2w[(lay * WD + o) * WD + k]
                                : ww[(lay * WD + o) * WD + (k - 128)];
            wcat[idx] = (f16)v;
        } else if (idx < 163840) {
            int i2 = idx - 131072;
            w1h[i2] = (f16)dec1w[i2];
        } else if (idx < 180224) {
            int i3 = idx - 163840;
            ecwh[i3] = (f16)ecw[i3];
        }
    } else {
        // wr/wi [lay][i][o][k] -> [lay][k][i][o]
        int twb = bid - 1728;                      // 0..1023
        const float* src = (twb >> 9) ? wi : wr;
        float*       dst = (twb >> 9) ? wiT : wrT;
        int xx = twb & 511;
        int ib = xx >> 7, i = xx & 127;
        __shared__ float tile[128][33];
        const float* s = src + ((size_t)(ib * WD + i) * WD) * MODES;
        for (int e = threadIdx.x; e < WD * MODES; e += 256) {
            int o = e >> 5, k = e & 31;
            tile[o][k] = s[e];
        }
        __syncthreads();
        float* d = dst + (size_t)ib * (MODES * WD * WD) + i * WD;
        for (int e = threadIdx.x; e < WD * MODES; e += 256) {
            int k = e >> 7, o = e & 127;
            d[(size_t)k * WD * WD + o] = tile[o][k];
        }
    }
}

// ---------------- encoder ----------------

__global__ __launch_bounds__(256) void k_enc_fused(const float* __restrict__ x,
        const int* __restrict__ src, const float* __restrict__ ew,
        const float* __restrict__ eb, f16* __restrict__ h1) {
    int tid = threadIdx.x;
    int t0 = blockIdx.x * 64;
    int b = t0 >> 13;
    const float* xg0 = x + (size_t)(b * 3 + 0) * NN;
    const float* xg1 = x + (size_t)(b * 3 + 1) * NN;
    const float* xg2 = x + (size_t)(b * 3 + 2) * NN;
    __shared__ float agg[64][8];
    {
        int nl = tid >> 2;
        int sub = tid & 3;
        int t = t0 + nl;
        int4 sl = *(const int4*)&src[t * DEG + sub * 4];
        int i0 = sl.x & (NN - 1), i1 = sl.y & (NN - 1);
        int i2 = sl.z & (NN - 1), i3 = sl.w & (NN - 1);
        float a0 = xg0[i0] + xg0[i1] + xg0[i2] + xg0[i3];
        float a1 = xg1[i0] + xg1[i1] + xg1[i2] + xg1[i3];
        float a2 = xg2[i0] + xg2[i1] + xg2[i2] + xg2[i3];
        a0 += __shfl_xor(a0, 1); a0 += __shfl_xor(a0, 2);
        a1 += __shfl_xor(a1, 1); a1 += __shfl_xor(a1, 2);
        a2 += __shfl_xor(a2, 1); a2 += __shfl_xor(a2, 2);
        if (sub == 0) {
            int n_ = t & (NN - 1);
            float xi0 = xg0[n_], xi1 = xg1[n_], xi2 = xg2[n_];
            agg[nl][0] = xi0; agg[nl][1] = xi1; agg[nl][2] = xi2;
            agg[nl][3] = (a0 + xi0) * (1.f / NEDGE) - xi0;
            agg[nl][4] = (a1 + xi1) * (1.f / NEDGE) - xi1;
            agg[nl][5] = (a2 + xi2) * (1.f / NEDGE) - xi2;
        }
    }
    __syncthreads();
    int o = tid & 127, half = tid >> 7;
    const float* w = ew + o * 6;
    float w0 = w[0], w1 = w[1], w2 = w[2], w3 = w[3], w4 = w[4], w5 = w[5];
    float bb = eb[o];
    #pragma unroll 4
    for (int g = 0; g < 32; ++g) {
        int n2 = half * 32 + g;
        float acc = bb + w0 * agg[n2][0] + w1 * agg[n2][1] + w2 * agg[n2][2]
                       + w3 * agg[n2][3] + w4 * agg[n2][4] + w5 * agg[n2][5];
        h1[(size_t)(t0 + n2) * WD + o] = (f16)gelu_f(acc);
    }
}

// gather: 4 nodes per wave-instruction, 32 nodes/block. At[node][c] stride 136.
__device__ __forceinline__ void gather4_to_lds(const f16* __restrict__ hin,
        const int* __restrict__ src, int t0, int tid, f16* At) {
    int wv = tid >> 6;
    int lane = tid & 63;
    int nd = lane >> 4;
    int cl = lane & 15;
    #pragma unroll
    for (int it = 0; it < 2; ++it) {
        int nl = wv * 8 + it * 4 + nd;
        int t = t0 + nl;
        f16x8 v = *(const f16x8*)&hin[(size_t)t * WD + cl * 8];
        float a0 = (float)v[0], a1 = (float)v[1], a2 = (float)v[2], a3 = (float)v[3];
        float a4 = (float)v[4], a5 = (float)v[5], a6 = (float)v[6], a7 = (float)v[7];
        const int* sl = src + t * DEG;
        #pragma unroll
        for (int d = 0; d < DEG; ++d) {
            int nb = sl[d];
            f16x8 u = *(const f16x8*)&hin[(size_t)nb * WD + cl * 8];
            a0 += (float)u[0]; a1 += (float)u[1]; a2 += (float)u[2]; a3 += (float)u[3];
            a4 += (float)u[4]; a5 += (float)u[5]; a6 += (float)u[6]; a7 += (float)u[7];
        }
        const float sc = 1.f / NEDGE;
        f16x8 r;
        r[0] = (f16)(a0 * sc); r[1] = (f16)(a1 * sc); r[2] = (f16)(a2 * sc); r[3] = (f16)(a3 * sc);
        r[4] = (f16)(a4 * sc); r[5] = (f16)(a5 * sc); r[6] = (f16)(a6 * sc); r[7] = (f16)(a7 * sc);
        *(f16x8*)&At[nl * 136 + cl * 8] = r;
    }
}

// gather 32-node mean -> MFMA (A=ecwh) -> h f16 [b][c][n]
__global__ __launch_bounds__(256, 4) void k_gather_lin_mfma(
        const f16* __restrict__ hin, const int* __restrict__ src,
        const f16* __restrict__ ecwh, const float* __restrict__ bias,
        f16* __restrict__ outp) {
    int tid = threadIdx.x;
    int ebid = swz1024(blockIdx.x);
    int t0 = ebid * 32;
    int b = ebid >> 8;
    int n0 = (ebid & 255) * 32;
    __shared__ f16 At[32 * 136];
    gather4_to_lds(hin, src, t0, tid, At);
    __syncthreads();
    int w = tid >> 6, l = tid & 63, lg = l >> 4, ln = l & 15;
    f32x4 acc[2][2] = {};
    #pragma unroll
    for (int kc = 0; kc < 4; ++kc) {
        f16x8 wa[2], ab[2];
        #pragma unroll
        for (int i = 0; i < 2; ++i)
            wa[i] = *(const f16x8*)&ecwh[((2 * w + i) * 16 + ln) * WD + kc * 32 + lg * 8];
        #pragma unroll
        for (int j = 0; j < 2; ++j)
            ab[j] = *(const f16x8*)&At[(j * 16 + ln) * 136 + kc * 32 + lg * 8];
        #pragma unroll
        for (int i = 0; i < 2; ++i)
            #pragma unroll
            for (int j = 0; j < 2; ++j)
                acc[i][j] = __builtin_amdgcn_mfma_f32_16x16x32_f16(wa[i], ab[j], acc[i][j], 0, 0, 0);
    }
    #pragma unroll
    for (int i = 0; i < 2; ++i) {
        int cb = (2 * w + i) * 16 + lg * 4;
        float b0 = bias[cb], b1 = bias[cb + 1], b2 = bias[cb + 2], b3 = bias[cb + 3];
        #pragma unroll
        for (int j = 0; j < 2; ++j) {
            int n_ = n0 + j * 16 + ln;
            outp[(size_t)(b * WD + cb + 0) * NN + n_] = (f16)(acc[i][j][0] + b0);
            outp[(size_t)(b * WD + cb + 1) * NN + n_] = (f16)(acc[i][j][1] + b1);
            outp[(size_t)(b * WD + cb + 2) * NN + n_] = (f16)(acc[i][j][2] + b2);
            outp[(size_t)(b * WD + cb + 3) * NN + n_] = (f16)(acc[i][j][3] + b3);
        }
    }
}

// ---------------- FNO block pieces ----------------

// DFT via MFMA + fused sum-of-squares: part[sp][512r][64kc], sqp[sp][512r]
__global__ __launch_bounds__(256, 2) void k_dft_mfma(const f16* __restrict__ h,
        const f16* __restrict__ tknh, float* __restrict__ part,
        float* __restrict__ sqp) {
    int bid = blockIdx.x;
    int sp = bid >> 3;                   // 0..31
    int r0 = (bid & 7) * 64;
    int wv = threadIdx.x >> 6, l = threadIdx.x & 63, lg = l >> 4, ln = l & 15;
    int row = r0 + wv * 16;
    f32x4 acc[4] = {};
    const f16* ha = h + (size_t)(row + ln) * NN + sp * 256 + lg * 8;
    const f16* tb = tknh + (size_t)ln * NN + sp * 256 + lg * 8;
    float sq = 0.f;
    #pragma unroll
    for (int st = 0; st < 8; ++st) {
        f16x8 a = *(const f16x8*)&ha[st * 32];
        #pragma unroll
        for (int j = 0; j < 8; ++j) { float f = (float)a[j]; sq += f * f; }
        #pragma unroll
        for (int tj = 0; tj < 4; ++tj) {
            f16x8 b = *(const f16x8*)&tb[(size_t)(tj * 16) * NN + st * 32];
            acc[tj] = __builtin_amdgcn_mfma_f32_16x16x32_f16(a, b, acc[tj], 0, 0, 0);
        }
    }
    float* pr = part + ((size_t)sp * 512 + row) * 64;
    #pragma unroll
    for (int tj = 0; tj < 4; ++tj)
        #pragma unroll
        for (int q = 0; q < 4; ++q)
            pr[(lg * 4 + q) * 64 + tj * 16 + ln] = acc[tj][q];
    sq += __shfl_xor(sq, 16);
    sq += __shfl_xor(sq, 32);
    if (lg == 0) sqp[sp * 512 + row + ln] = sq;
}

// stats from part[kc=0] + sqp; combine partials; write vf. No h re-read.
__global__ __launch_bounds__(256) void k_dft_fin3(const float* __restrict__ part,
        const float* __restrict__ sqp, float* __restrict__ vf) {
    int row = blockIdx.x * 4 + (threadIdx.x >> 6);
    int lane = threadIdx.x & 63;
    float D = 0.f;
    #pragma unroll
    for (int p = 0; p < 32; ++p)
        D += part[(size_t)(p * 512 + row) * 64 + lane];
    float sq = (lane < 32) ? sqp[lane * 512 + row] : 0.f;
    sq += __shfl_xor(sq, 1);
    sq += __shfl_xor(sq, 2);
    sq += __shfl_xor(sq, 4);
    sq += __shfl_xor(sq, 8);
    sq += __shfl_xor(sq, 16);
    sq += __shfl_xor(sq, 32);
    float D0 = __shfl(D, 0);
    float mu  = D0 * (1.f / NN);
    float var = sq * (1.f / NN) - mu * mu;
    float s1  = 1.f / sqrtf(fmaxf(var, 0.f) + 1e-5f);
    float v;
    if (lane < 2) v = 0.f;
    else          v = (lane & 1) ? -D * s1 : D * s1;
    vf[row * 64 + lane] = v;
}

__global__ __launch_bounds__(128) void k_spec(const float* __restrict__ vf,
        const float* __restrict__ wrT, const float* __restrict__ wiT,
        float* __restrict__ of, int lay) {
    int b = blockIdx.x / 31;
    int k = blockIdx.x - b * 31 + 1;
    int o = threadIdx.x;
    __shared__ float vr[WD], vi[WD];
    vr[o] = vf[(b * WD + o) * 64 + 2 * k];
    vi[o] = vf[(b * WD + o) * 64 + 2 * k + 1];
    __syncthreads();
    const float* wrk = wrT + ((size_t)(lay * MODES + k) * WD) * WD + o;
    const float* wik = wiT + ((size_t)(lay * MODES + k) * WD) * WD + o;
    float ore = 0.f, oim = 0.f;
    for (int i = 0; i < WD; ++i) {
        float a = vr[i], bq = vi[i];
        float w0 = wrk[i * WD], w1 = wik[i * WD];
        ore += a * w0 - bq * w1;
        oim += a * w1 + bq * w0;
    }
    of[(b * WD + o) * 64 + 2 * k]     = ore;
    of[(b * WD + o) * 64 + 2 * k + 1] = oim;
}

// sigma2 + fold f1_w -> GB f16 [b][c][64] (slots 0..61 = kc 2..63; 62,63 = 0)
__global__ __launch_bounds__(256) void k_coef(const float* __restrict__ of,
        const float* __restrict__ f1w, f16* __restrict__ GB) {
    int b = blockIdx.x >> 3;
    int c0 = (blockIdx.x & 7) * 16;
    __shared__ float ofl[WD][66];
    __shared__ float fw[16][WD];
    __shared__ float scl[WD];
    for (int e = threadIdx.x; e < WD * 64; e += 256) {
        int o = e >> 6, kc = e & 63;
        ofl[o][kc] = of[(b * WD + o) * 64 + kc];
    }
    for (int e = threadIdx.x; e < 16 * WD; e += 256) {
        int cl = e >> 7, i = e & 127;
        fw[cl][i] = f1w[(c0 + cl) * WD + i];
    }
    __syncthreads();
    if (threadIdx.x < WD) {
        int o = threadIdx.x;
        float s = 0.f;
        for (int kc = 2; kc < 64; ++kc) { float v = ofl[o][kc]; s += v * v; }
        float var = s * (2.f / ((float)NN * (float)NN));
        scl[o] = (2.f / (float)NN) / sqrtf(var + 1e-5f);
    }
    __syncthreads();
    for (int e = threadIdx.x; e < 16 * 62; e += 256) {
        int cl = e / 62, kc = e - cl * 62 + 2;
        float a = 0.f;
        for (int o = 0; o < WD; ++o)
            a += fw[cl][o] * (ofl[o][kc] * scl[o]);
        if (kc & 1) a = -a;
        GB[(b * WD + c0 + cl) * 64 + (kc - 2)] = (f16)a;
    }
    if (threadIdx.x < 32) {
        int cl = threadIdx.x >> 1;
        GB[(b * WD + c0 + cl) * 64 + 62 + (threadIdx.x & 1)] = (f16)0.f;
    }
}

// fused FNO tail (f16 h in/out): t = gelu(G@tbl + f1b); hnew = gelu(f2@t + w@h + b)
// When hfo != nullptr, ALSO writes hnew node-major (replaces k_tr_hf).
__global__ __launch_bounds__(256, 2) void k_fno(const f16* __restrict__ hc,
        const f16* __restrict__ GB, const f16* __restrict__ nkbf,
        const f16* __restrict__ wcat, const float* __restrict__ f1b,
        const float* __restrict__ f2b, const float* __restrict__ wb,
        f16* __restrict__ hn, f16* __restrict__ hfo) {
    int tid = threadIdx.x;
    int b = blockIdx.x >> 7;
    int n0 = (blockIdx.x & 127) * 64;
    int w = tid >> 6, l = tid & 63, lg = l >> 4, ln = l & 15;
    __shared__ f16 tS[64 * 136];   // [n][c]
    __shared__ f16 hS[64 * 136];
    f16x8 hreg[4];
    #pragma unroll
    for (int p = 0; p < 4; ++p) {
        int idx = p * 256 + tid;
        int c = idx >> 3, n8 = idx & 7;
        hreg[p] = *(const f16x8*)&hc[(size_t)(b * WD + c) * NN + n0 + n8 * 8];
    }
    // stage 1: t = G @ tbl  (K=64)
    f32x4 acc1[2][4] = {};
    #pragma unroll
    for (int kc = 0; kc < 2; ++kc) {
        f16x8 ga[2], tb[4];
        #pragma unroll
        for (int i = 0; i < 2; ++i)
            ga[i] = *(const f16x8*)&GB[(size_t)(b * WD + (2 * w + i) * 16 + ln) * 64 + kc * 32 + lg * 8];
        #pragma unroll
        for (int j = 0; j < 4; ++j)
            tb[j] = *(const f16x8*)&nkbf[(size_t)(n0 + j * 16 + ln) * 64 + kc * 32 + lg * 8];
        #pragma unroll
        for (int i = 0; i < 2; ++i)
            #pragma unroll
            for (int j = 0; j < 4; ++j)
                acc1[i][j] = __builtin_amdgcn_mfma_f32_16x16x32_f16(ga[i], tb[j], acc1[i][j], 0, 0, 0);
    }
    #pragma unroll
    for (int i = 0; i < 2; ++i) {
        int cb = (2 * w + i) * 16 + lg * 4;
        float b0 = f1b[cb], b1 = f1b[cb + 1], b2 = f1b[cb + 2], b3 = f1b[cb + 3];
        #pragma unroll
        for (int j = 0; j < 4; ++j) {
            int n_ = j * 16 + ln;
            f16x4 o4;
            o4[0] = (f16)gelu_f(acc1[i][j][0] + b0);
            o4[1] = (f16)gelu_f(acc1[i][j][1] + b1);
            o4[2] = (f16)gelu_f(acc1[i][j][2] + b2);
            o4[3] = (f16)gelu_f(acc1[i][j][3] + b3);
            *(f16x4*)&tS[n_ * 136 + cb] = o4;
        }
    }
    #pragma unroll
    for (int p = 0; p < 4; ++p) {
        int idx = p * 256 + tid;
        int c = idx >> 3, n8 = idx & 7;
        #pragma unroll
        for (int q = 0; q < 8; ++q)
            hS[(n8 * 8 + q) * 136 + c] = hreg[p][q];
    }
    __syncthreads();
    // stage 2: D = Wcat @ [t ; h]  (K=256)
    f32x4 acc2[2][4] = {};
    #pragma unroll
    for (int kc = 0; kc < 8; ++kc) {
        const f16* Xs = (kc < 4) ? (tS + kc * 32) : (hS + (kc - 4) * 32);
        f16x8 wa[2], xb[4];
        #pragma unroll
        for (int i = 0; i < 2; ++i)
            wa[i] = *(const f16x8*)&wcat[(size_t)((2 * w + i) * 16 + ln) * 256 + kc * 32 + lg * 8];
        #pragma unroll
        for (int j = 0; j < 4; ++j)
            xb[j] = *(const f16x8*)&Xs[(j * 16 + ln) * 136 + lg * 8];
        #pragma unroll
        for (int i = 0; i < 2; ++i)
            #pragma unroll
            for (int j = 0; j < 4; ++j)
                acc2[i][j] = __builtin_amdgcn_mfma_f32_16x16x32_f16(wa[i], xb[j], acc2[i][j], 0, 0, 0);
    }
    #pragma unroll
    for (int i = 0; i < 2; ++i) {
        int ob = (2 * w + i) * 16 + lg * 4;
        float b0 = f2b[ob] + wb[ob];
        float b1 = f2b[ob + 1] + wb[ob + 1];
        float b2 = f2b[ob + 2] + wb[ob + 2];
        float b3 = f2b[ob + 3] + wb[ob + 3];
        #pragma unroll
        for (int j = 0; j < 4; ++j) {
            int n_ = n0 + j * 16 + ln;
            f16 v0 = (f16)gelu_f(acc2[i][j][0] + b0);
            f16 v1 = (f16)gelu_f(acc2[i][j][1] + b1);
            f16 v2 = (f16)gelu_f(acc2[i][j][2] + b2);
            f16 v3 = (f16)gelu_f(acc2[i][j][3] + b3);
            hn[(size_t)(b * WD + ob + 0) * NN + n_] = v0;
            hn[(size_t)(b * WD + ob + 1) * NN + n_] = v1;
            hn[(size_t)(b * WD + ob + 2) * NN + n_] = v2;
            hn[(size_t)(b * WD + ob + 3) * NN + n_] = v3;
            if (hfo) {
                f16x4 o4; o4[0] = v0; o4[1] = v1; o4[2] = v2; o4[3] = v3;
                *(f16x4*)&hfo[(size_t)(b * NN + n_) * WD + ob] = o4;
            }
        }
    }
}

// ---------------- decoder ----------------

__global__ __launch_bounds__(256, 4) void k_dec_mfma(const f16* __restrict__ hf,
        const int* __restrict__ src, const f16* __restrict__ w1h,
        const float* __restrict__ b1, const float* __restrict__ w3,
        const float* __restrict__ b3, float* __restrict__ z) {
    int tid = threadIdx.x;
    int t0 = swz1024(blockIdx.x) * 32;
    __shared__ f16 At[32 * 136];
    __shared__ float zl[16 * 32];
    gather4_to_lds(hf, src, t0, tid, At);
    __syncthreads();
    int w = tid >> 6, l = tid & 63, lg = l >> 4, ln = l & 15;
    f32x4 acc[4][2] = {};
    #pragma unroll
    for (int kc = 0; kc < 4; ++kc) {
        f16x8 wa[4], ab[2];
        #pragma unroll
        for (int u = 0; u < 4; ++u)
            wa[u] = *(const f16x8*)&w1h[(size_t)((w * 4 + u) * 16 + ln) * WD + kc * 32 + lg * 8];
        #pragma unroll
        for (int j = 0; j < 2; ++j)
            ab[j] = *(const f16x8*)&At[(j * 16 + ln) * 136 + kc * 32 + lg * 8];
        #pragma unroll
        for (int u = 0; u < 4; ++u)
            #pragma unroll
            for (int j = 0; j < 2; ++j)
                acc[u][j] = __builtin_amdgcn_mfma_f32_16x16x32_f16(wa[u], ab[j], acc[u][j], 0, 0, 0);
    }
    float pz[2] = {0.f, 0.f};
    #pragma unroll
    for (int u = 0; u < 4; ++u) {
        int jb = (w * 4 + u) * 16 + lg * 4;
        float b1r0 = b1[jb], b1r1 = b1[jb + 1], b1r2 = b1[jb + 2], b1r3 = b1[jb + 3];
        float w3r0 = w3[jb], w3r1 = w3[jb + 1], w3r2 = w3[jb + 2], w3r3 = w3[jb + 3];
        #pragma unroll
        for (int j = 0; j < 2; ++j) {
            pz[j] += w3r0 * gelu_f(acc[u][j][0] + b1r0);
            pz[j] += w3r1 * gelu_f(acc[u][j][1] + b1r1);
            pz[j] += w3r2 * gelu_f(acc[u][j][2] + b1r2);
            pz[j] += w3r3 * gelu_f(acc[u][j][3] + b1r3);
        }
    }
    #pragma unroll
    for (int j = 0; j < 2; ++j)
        zl[(w * 4 + lg) * 32 + j * 16 + ln] = pz[j];
    __syncthreads();
    if (tid < 32) {
        float s = b3[0];
        #pragma unroll
        for (int g = 0; g < 16; ++g) s += zl[g * 32 + tid];
        z[t0 + tid] = s;
    }
}

__global__ __launch_bounds__(256) void k_out(const float* __restrict__ z,
        const int* __restrict__ src, float* __restrict__ outp) {
    int t = blockIdx.x * 256 + threadIdx.x;
    if (t >= NTOT) return;
    const int* sl = src + t * DEG;
    float acc = z[t];
    #pragma unroll
    for (int d = 0; d < DEG; ++d) acc += z[sl[d]];
    outp[t] = acc * (1.f / NEDGE);
}

// ---------------- host launcher ----------------

extern "C" void kernel_launch(void* const* d_in, const int* in_sizes, int n_in,
                              void* d_out, int out_size, void* d_ws, size_t ws_size,
                              hipStream_t stream) {
    const float* x       = (const float*)d_in[0];
    const int*   ei      = (const int*)  d_in[1];   // row0 = src
    const float* enc_e_w = (const float*)d_in[2];
    const float* enc_e_b = (const float*)d_in[3];
    const float* enc_c_w = (const float*)d_in[4];
    const float* enc_c_b = (const float*)d_in[5];
    const float* wr      = (const float*)d_in[6];
    const float* wi      = (const float*)d_in[7];
    const float* w_w     = (const float*)d_in[8];
    const float* w_b     = (const float*)d_in[9];
    const float* f1_w    = (const float*)d_in[10];
    const float* f1_b    = (const float*)d_in[11];
    const float* f2_w    = (const float*)d_in[12];
    const float* f2_b    = (const float*)d_in[13];
    const float* dec1_w  = (const float*)d_in[14];
    const float* dec1_b  = (const float*)d_in[15];
    const float* dec3_w  = (const float*)d_in[16];
    const float* dec3_b  = (const float*)d_in[17];
    float* outp = (float*)d_out;
    float* ws = (float*)d_ws;

    float* wrT   = ws;                         // 2,097,152
    float* wiT   = wrT + 2097152;              // 2,097,152
    float* part  = wiT + 2097152;              // 1,048,576 (32 splits)
    float* sqp   = part + 1048576;             // 16,384
    float* zb    = sqp + 16384;                // 32,768
    float* vf    = zb + 32768;                 // 32,768
    float* of    = vf + 32768;                 // 32,768
    f16* h1h  = (f16*)(of + 32768);            // 4,194,304 f16 (enc feat / dec hf)
    f16* H0   = h1h + 4194304;                 // 4,194,304
    f16* H1   = H0 + 4194304;                  // 4,194,304
    f16* nkbf = H1 + 4194304;                  // 524,288
    f16* tknh = nkbf + 524288;                 // 524,288
    f16* wcatB= tknh + 524288;                 // 131,072
    f16* w1h  = wcatB + 131072;                // 32,768
    f16* ecwh = w1h + 32768;                   // 16,384
    f16* GB   = ecwh + 16384;                  // 32,768
    f16* hfh  = h1h;

    k_setup<<<2752, 256, 0, stream>>>(f2_w, w_w, dec1_w, enc_c_w, wr, wi,
                                      nkbf, tknh, wcatB, w1h, ecwh, wrT, wiT);

    // encoder
    k_enc_fused<<<512, 256, 0, stream>>>(x, ei, enc_e_w, enc_e_b, h1h);
    k_gather_lin_mfma<<<1024, 256, 0, stream>>>(h1h, ei, ecwh, enc_c_b, H0);

    for (int lay = 0; lay < 4; ++lay) {
        f16* hc = (lay & 1) ? H1 : H0;
        f16* hn = (lay & 1) ? H0 : H1;
        k_dft_mfma<<<256, 256, 0, stream>>>(hc, tknh, part, sqp);
        k_dft_fin3<<<128, 256, 0, stream>>>(part, sqp, vf);
        k_spec<<<124, 128, 0, stream>>>(vf, wrT, wiT, of, lay);
        k_coef<<<32, 256, 0, stream>>>(of, f1_w + lay * WD * WD, GB);
        k_fno<<<512, 256, 0, stream>>>(hc, GB, nkbf, wcatB + lay * WD * 256,
                                       f1_b + lay * WD, f2_b + lay * WD,
                                       w_b + lay * WD, hn,
                                       (lay == 3) ? hfh : (f16*)nullptr);
    }
    // final h in H0, node-major copy in hfh

    k_dec_mfma<<<1024, 256, 0, stream>>>(hfh, ei, w1h, dec1_b, dec3_w, dec3_b, zb);
    k_out<<<128, 256, 0, stream>>>(zb, ei, outp);
}